// Round 6
// baseline (655.482 us; speedup 1.0000x reference)
//
#include <hip/hip_runtime.h>
#include <cstdint>
#include <cstddef>

// ---------------------------------------------------------------------------
// AutoFormer forward, MI355X. ALL inputs/outputs are FP32 (per reference).
// Q/K projections: MFMA GEMM reading fp32 A directly; A is reg-staged with
// async split (loads issued pre-compute, convert+ds_write post-compute),
// B (bf16 WT) double-buffered via global_load_lds. One barrier per K-step.
// corr via FFT, radix-8/4 Stockham; top-22 via radix-select; softmax mod-8.
// Output projection fused with the mod-8 broadcast (osmall_bcast).
// B=8, L=2048, D=1024, H=16, E=64, TOPK=22.
//
// Buffers:
//   ws:    WqT/WkT (bf16, 2 MiB ea), Qt (bf16 [B*D,L], 32 MiB), smalls (<1 MiB)
//   d_out: out0 region [16M fp32] doubles as Kt/corrWs bf16 staging (32 MiB);
//          corr_topk aliases corr rows over Kt; corr_transpose consumes them
//          into out1; osmall_bcast overwrites out0 LAST.
// ---------------------------------------------------------------------------

#define TOPK 22

typedef __attribute__((ext_vector_type(8))) short short8;
typedef __attribute__((ext_vector_type(4))) float f32x4;

__device__ __forceinline__ float bf2f(unsigned short u) {
  union { unsigned int i; float f; } w;
  w.i = ((unsigned int)u) << 16;
  return w.f;
}
__device__ __forceinline__ unsigned short f2bf(float f) {
  union { float f; unsigned int i; } w;
  w.f = f;
  unsigned int x = w.i;
  x += 0x7fffu + ((x >> 16) & 1u);  // RNE
  return (unsigned short)(x >> 16);
}

__device__ __forceinline__ void gload_lds16(const void* g, void* l) {
  __builtin_amdgcn_global_load_lds(
      (const __attribute__((address_space(1))) unsigned int*)g,
      (__attribute__((address_space(3))) unsigned int*)l, 16, 0, 0);
}

__device__ __forceinline__ float2 make2(float x, float y) { float2 r; r.x = x; r.y = y; return r; }
__device__ __forceinline__ float2 cadd(float2 a, float2 b) { return make2(a.x + b.x, a.y + b.y); }
__device__ __forceinline__ float2 csub(float2 a, float2 b) { return make2(a.x - b.x, a.y - b.y); }
__device__ __forceinline__ float2 cmul(float2 a, float2 b) {
  return make2(a.x * b.x - a.y * b.y, a.x * b.y + a.y * b.x);
}

// padded complex->float index: 2 pad floats per 32 complex; keeps 8B align.
__device__ __forceinline__ int cfi(int u) { return 2 * u + (((u) >> 5) << 1); }

// 8-point DFT in registers. INV=false: e^{-2pi i/8}; INV=true: conj.
template <bool INV>
__device__ __forceinline__ void dft8(float2 (&v)[8]) {
  const float C = 0.70710678118654752f;
  // evens DFT4
  float2 s0 = cadd(v[0], v[4]), s1 = csub(v[0], v[4]);
  float2 s2 = cadd(v[2], v[6]), s3 = csub(v[2], v[6]);
  float2 E0 = cadd(s0, s2), E2 = csub(s0, s2);
  float2 E1, E3;
  if (!INV) { E1 = make2(s1.x + s3.y, s1.y - s3.x); E3 = make2(s1.x - s3.y, s1.y + s3.x); }
  else      { E1 = make2(s1.x - s3.y, s1.y + s3.x); E3 = make2(s1.x + s3.y, s1.y - s3.x); }
  // odds DFT4
  float2 q0 = cadd(v[1], v[5]), q1 = csub(v[1], v[5]);
  float2 q2 = cadd(v[3], v[7]), q3 = csub(v[3], v[7]);
  float2 O0 = cadd(q0, q2), O2 = csub(q0, q2);
  float2 O1, O3;
  if (!INV) { O1 = make2(q1.x + q3.y, q1.y - q3.x); O3 = make2(q1.x - q3.y, q1.y + q3.x); }
  else      { O1 = make2(q1.x - q3.y, q1.y + q3.x); O3 = make2(q1.x + q3.y, q1.y - q3.x); }
  // twiddle odds by w8^m
  float2 T0 = O0, T1, T2, T3;
  if (!INV) {
    T1 = make2(C * (O1.x + O1.y), C * (O1.y - O1.x));   // *(1-i)/sqrt2
    T2 = make2(O2.y, -O2.x);                            // *(-i)
    T3 = make2(C * (O3.y - O3.x), -C * (O3.x + O3.y));  // *(-(1+i)/sqrt2)
  } else {
    T1 = make2(C * (O1.x - O1.y), C * (O1.x + O1.y));   // *(1+i)/sqrt2
    T2 = make2(-O2.y, O2.x);                            // *(+i)
    T3 = make2(-C * (O3.x + O3.y), C * (O3.x - O3.y));  // *((-1+i)/sqrt2)
  }
  v[0] = cadd(E0, T0); v[4] = csub(E0, T0);
  v[1] = cadd(E1, T1); v[5] = csub(E1, T1);
  v[2] = cadd(E2, T2); v[6] = csub(E2, T2);
  v[3] = cadd(E3, T3); v[7] = csub(E3, T3);
}

template <bool INV>
__device__ __forceinline__ void dft4(float2 (&v)[4]) {
  float2 s0 = cadd(v[0], v[2]), s1 = csub(v[0], v[2]);
  float2 s2 = cadd(v[1], v[3]), s3 = csub(v[1], v[3]);
  v[0] = cadd(s0, s2); v[2] = csub(s0, s2);
  if (!INV) { v[1] = make2(s1.x + s3.y, s1.y - s3.x); v[3] = make2(s1.x - s3.y, s1.y + s3.x); }
  else      { v[1] = make2(s1.x - s3.y, s1.y + s3.x); v[3] = make2(s1.x + s3.y, s1.y - s3.x); }
}

// Stockham radix-8 LDS stage. Reads src[j+256m], writes dst[d+m*NS],
// d = (j div NS)*8NS + r, twiddle w^(r*m), w = e^{sigma*2pi i*r/(8NS)}.
template <int NS, bool INV>
__device__ __forceinline__ void stage8(const float* __restrict__ src,
                                       float* __restrict__ dst, int tid) {
  float2 v[8];
#pragma unroll
  for (int m = 0; m < 8; ++m)
    v[m] = *reinterpret_cast<const float2*>(src + cfi(tid + (m << 8)));
  if constexpr (NS > 1) {
    const int r = tid & (NS - 1);
    const float rev = (INV ? (1.0f / (8 * NS)) : (-1.0f / (8 * NS))) * (float)r;
    float2 w1; w1.x = __builtin_amdgcn_cosf(rev); w1.y = __builtin_amdgcn_sinf(rev);
    const float2 w2 = cmul(w1, w1);
    const float2 w3 = cmul(w2, w1);
    const float2 w4 = cmul(w2, w2);
    const float2 w5 = cmul(w4, w1);
    const float2 w6 = cmul(w4, w2);
    const float2 w7 = cmul(w4, w3);
    v[1] = cmul(v[1], w1); v[2] = cmul(v[2], w2); v[3] = cmul(v[3], w3);
    v[4] = cmul(v[4], w4); v[5] = cmul(v[5], w5); v[6] = cmul(v[6], w6);
    v[7] = cmul(v[7], w7);
  }
  dft8<INV>(v);
  const int r2 = tid & (NS - 1);
  const int d = ((tid & ~(NS - 1)) << 3) | r2;
#pragma unroll
  for (int m = 0; m < 8; ++m)
    *reinterpret_cast<float2*>(dst + cfi(d + m * NS)) = v[m];
}

// radix-select pick phase: wave 0 scans a 256-bin histogram from the top,
// finds bin containing the 'need'-th largest; writes {bin, need_within_bin}.
__device__ __forceinline__ void radix_pick(const unsigned int* h,
                                           unsigned int* sb,
                                           unsigned int need, int tid) {
  if (tid < 64) {
    const unsigned int c0 = h[4 * tid + 0];
    const unsigned int c1 = h[4 * tid + 1];
    const unsigned int c2 = h[4 * tid + 2];
    const unsigned int c3 = h[4 * tid + 3];
    const unsigned int g = c0 + c1 + c2 + c3;
    unsigned int S = g;  // suffix-inclusive scan over 64 groups
#pragma unroll
    for (int off = 1; off < 64; off <<= 1) {
      const unsigned int o = __shfl_down(S, off);
      if (tid + off < 64) S += o;
    }
    unsigned int A = S - g;  // count in bins strictly above this group
    int pick = -1;
    unsigned int nn = 0;
    const unsigned int cc[4] = {c0, c1, c2, c3};
#pragma unroll
    for (int j = 3; j >= 0; --j) {
      if (pick < 0) {
        if (A < need && need <= A + cc[j]) { pick = j; nn = need - A; }
        else A += cc[j];
      }
    }
    if (pick >= 0) { sb[0] = (unsigned int)(4 * tid + pick); sb[1] = nn; }
  }
}

// ---------------------------------------------------------------------------
// 1. Weight transpose + fp32->bf16: WT[n][k] = bf16(W[k][n]), z=0:Wq z=1:Wk
// ---------------------------------------------------------------------------
__global__ __launch_bounds__(256) void transpose_w(
    const float* __restrict__ Wq, const float* __restrict__ Wk,
    unsigned short* __restrict__ WqT, unsigned short* __restrict__ WkT) {
  __shared__ unsigned short T[64][72];
  const float* src = blockIdx.z ? Wk : Wq;
  unsigned short* dst = blockIdx.z ? WkT : WqT;
  const int k0 = blockIdx.x * 64;
  const int n0 = blockIdx.y * 64;
  const int c = threadIdx.x & 63;
  const int r0 = threadIdx.x >> 6;
#pragma unroll
  for (int p = 0; p < 16; ++p) {
    const int r = r0 + 4 * p;  // k-local
    T[c][r] = f2bf(src[(size_t)(k0 + r) * 1024 + n0 + c]);  // coalesced read
  }
  __syncthreads();
#pragma unroll
  for (int p = 0; p < 16; ++p) {
    const int nn = r0 + 4 * p;  // n-local
    dst[(size_t)(n0 + nn) * 1024 + k0 + c] = T[nn][c];  // coalesced write
  }
}

// ---------------------------------------------------------------------------
// 2. MFMA bf16 GEMM, fp32 A input, async-split staging:
//    out = bf16(A)[16384,1024] @ WT^T + bias, written transposed bf16 as
//    outT[b*1024+n][l]. Tile 128x128, BK=32, 4 waves, 16x16x32 MFMA.
//    Per K-step: {issue A float4 loads (t+1), issue B gload_lds (t+1)} ->
//    compute tile t (ds_read+MFMA) -> {convert A regs, ds_write buf^1} ->
//    ONE __syncthreads(). A conversion VALU lands in the compute shadow;
//    global latency spans the whole compute phase. LDS 2x16KB; epilogue
//    reuses all 32KB as Cs. XCD swizzle: XCD k owns N-tile k.
// ---------------------------------------------------------------------------
__global__ __launch_bounds__(256, 4) void gemm_qk(
    const float* __restrict__ A,             // fp32 [16384][1024]
    const unsigned short* __restrict__ WT,   // bf16 [1024][1024] [n][k]
    const float* __restrict__ bias,
    unsigned short* __restrict__ outT) {
  __shared__ __align__(16) unsigned short smem[16384];  // 32 KB

  const int tid = threadIdx.x;
  const int lane = tid & 63;
  const int w = tid >> 6;
  const int wr = w >> 1, wc = w & 1;
  // XCD-aware swizzle over 1024 blocks (1024 % 8 == 0 -> bijective)
  const int wg = blockIdx.x;
  const int sid = ((wg & 7) << 7) | (wg >> 3);
  const int m0 = (sid & 127) << 7;  // M-tile
  const int n0 = (sid >> 7) << 7;   // N-tile
  const int l15 = lane & 15;
  const int quad = lane >> 4;
  const int srow = lane >> 2;       // B staging: row within 16-row chunk
  const int scol = (lane & 3) * 8;  // B staging: col (elements)

  // A staging ownership: chunks c = tid and tid+256; 8 fp32 each.
  const int ar0 = tid >> 2, akc0 = (tid & 3) * 8;
  const int ar1 = (tid + 256) >> 2, akc1 = ((tid + 256) & 3) * 8;
  const float* Ap0 = A + (size_t)(m0 + ar0) * 1024 + akc0;
  const float* Ap1 = A + (size_t)(m0 + ar1) * 1024 + akc1;
  const unsigned short* Bbase = WT + (size_t)n0 * 1024;

  f32x4 acc[4][4];
#pragma unroll
  for (int i = 0; i < 4; ++i)
#pragma unroll
    for (int j = 0; j < 4; ++j)
#pragma unroll
      for (int r = 0; r < 4; ++r) acc[i][j][r] = 0.f;

  float4 ra0, ra1, ra2, ra3;  // in-flight A tile (16 fp32)

  // ---- prologue: tile 0 -> buf 0 ----
  ra0 = *reinterpret_cast<const float4*>(Ap0);
  ra1 = *reinterpret_cast<const float4*>(Ap0 + 4);
  ra2 = *reinterpret_cast<const float4*>(Ap1);
  ra3 = *reinterpret_cast<const float4*>(Ap1 + 4);
  {
    unsigned short* Bs = smem + 4096;
#pragma unroll
    for (int i = 0; i < 2; ++i) {
      const int cc = w * 2 + i;
      const int row = cc * 16 + srow;
      gload_lds16(Bbase + (size_t)row * 1024 + scol, Bs + cc * 512);
    }
    unsigned short* As = smem;
    uint4 pa, pb;
    pa.x = f2bf(ra0.x) | ((unsigned int)f2bf(ra0.y) << 16);
    pa.y = f2bf(ra0.z) | ((unsigned int)f2bf(ra0.w) << 16);
    pa.z = f2bf(ra1.x) | ((unsigned int)f2bf(ra1.y) << 16);
    pa.w = f2bf(ra1.z) | ((unsigned int)f2bf(ra1.w) << 16);
    pb.x = f2bf(ra2.x) | ((unsigned int)f2bf(ra2.y) << 16);
    pb.y = f2bf(ra2.z) | ((unsigned int)f2bf(ra2.w) << 16);
    pb.z = f2bf(ra3.x) | ((unsigned int)f2bf(ra3.y) << 16);
    pb.w = f2bf(ra3.z) | ((unsigned int)f2bf(ra3.w) << 16);
    *reinterpret_cast<uint4*>(As + ar0 * 32 + akc0) = pa;
    *reinterpret_cast<uint4*>(As + ar1 * 32 + akc1) = pb;
  }
  __syncthreads();

  int cur = 0;
  for (int t = 0; t < 32; ++t) {
    // issue next-tile loads FIRST (fly across this step's compute)
    if (t < 31) {
      const int k0 = (t + 1) * 32;
      ra0 = *reinterpret_cast<const float4*>(Ap0 + k0);
      ra1 = *reinterpret_cast<const float4*>(Ap0 + k0 + 4);
      ra2 = *reinterpret_cast<const float4*>(Ap1 + k0);
      ra3 = *reinterpret_cast<const float4*>(Ap1 + k0 + 4);
      unsigned short* Bs = smem + ((cur ^ 1) << 13) + 4096;
#pragma unroll
      for (int i = 0; i < 2; ++i) {
        const int cc = w * 2 + i;
        const int row = cc * 16 + srow;
        gload_lds16(Bbase + (size_t)row * 1024 + k0 + scol, Bs + cc * 512);
      }
    }
    // compute on current buf
    {
      const unsigned short* As = smem + (cur << 13);
      const unsigned short* Bs = As + 4096;
      short8 af[4], bfr[4];
#pragma unroll
      for (int mt = 0; mt < 4; ++mt)
        af[mt] = *reinterpret_cast<const short8*>(As + (wr * 64 + mt * 16 + l15) * 32 + quad * 8);
#pragma unroll
      for (int nt = 0; nt < 4; ++nt)
        bfr[nt] = *reinterpret_cast<const short8*>(Bs + (wc * 64 + nt * 16 + l15) * 32 + quad * 8);
#pragma unroll
      for (int mt = 0; mt < 4; ++mt)
#pragma unroll
        for (int nt = 0; nt < 4; ++nt)
          acc[mt][nt] = __builtin_amdgcn_mfma_f32_16x16x32_bf16(af[mt], bfr[nt], acc[mt][nt], 0, 0, 0);
    }
    // convert + write next A tile (post-compute: loads have landed)
    if (t < 31) {
      unsigned short* As = smem + ((cur ^ 1) << 13);
      uint4 pa, pb;
      pa.x = f2bf(ra0.x) | ((unsigned int)f2bf(ra0.y) << 16);
      pa.y = f2bf(ra0.z) | ((unsigned int)f2bf(ra0.w) << 16);
      pa.z = f2bf(ra1.x) | ((unsigned int)f2bf(ra1.y) << 16);
      pa.w = f2bf(ra1.z) | ((unsigned int)f2bf(ra1.w) << 16);
      pb.x = f2bf(ra2.x) | ((unsigned int)f2bf(ra2.y) << 16);
      pb.y = f2bf(ra2.z) | ((unsigned int)f2bf(ra2.w) << 16);
      pb.z = f2bf(ra3.x) | ((unsigned int)f2bf(ra3.y) << 16);
      pb.w = f2bf(ra3.z) | ((unsigned int)f2bf(ra3.w) << 16);
      *reinterpret_cast<uint4*>(As + ar0 * 32 + akc0) = pa;
      *reinterpret_cast<uint4*>(As + ar1 * 32 + akc1) = pb;
    }
    __syncthreads();  // drains vmcnt (B gload_lds) + lgkm (A ds_write)
    cur ^= 1;
  }

  // epilogue: bias + pack transposed into LDS Cs[n_local][m_local] (bf16)
  unsigned short* Cs = smem;  // [128][128] bf16 = 32 KB
#pragma unroll
  for (int nt = 0; nt < 4; ++nt) {
    const int n_local = wc * 64 + nt * 16 + l15;
    const float bv = bias[n0 + n_local];
#pragma unroll
    for (int mt = 0; mt < 4; ++mt) {
      const int mbase = wr * 64 + mt * 16 + quad * 4;
#pragma unroll
      for (int r = 0; r < 4; ++r)
        Cs[n_local * 128 + mbase + r] = f2bf(acc[mt][nt][r] + bv);
    }
  }
  __syncthreads();

  const int b = m0 >> 11;    // m0 / 2048
  const int l0 = m0 & 2047;
  for (int it = tid; it < 2048; it += 256) {
    const int rowi = it >> 4;  // n_local
    const int ci = it & 15;    // 16B chunk
    uint4 v = *reinterpret_cast<const uint4*>(Cs + rowi * 128 + ci * 8);
    *reinterpret_cast<uint4*>(outT + (size_t)(b * 1024 + n0 + rowi) * 2048 + l0 + ci * 8) = v;
  }
}

// ---------------------------------------------------------------------------
// 3. V projection, rows l=0..7 only (the %8 quirk): vsmall[b*8+t][n] fp32
// ---------------------------------------------------------------------------
__global__ __launch_bounds__(256) void vsmall_kernel(
    const float* __restrict__ values,
    const float* __restrict__ Wv,
    const float* __restrict__ bv,
    float* __restrict__ out) {
  __shared__ float xr[1024];
  const int m = blockIdx.x;  // 0..63
  const int b = m >> 3, t = m & 7;
  const float* row = values + ((size_t)b * 2048 + t) * 1024;
  for (int i = threadIdx.x; i < 1024; i += 256) xr[i] = row[i];
  __syncthreads();
  const int n = blockIdx.y * 256 + threadIdx.x;
  float acc = 0.f;
#pragma unroll 8
  for (int k = 0; k < 1024; ++k) acc += xr[k] * Wv[(size_t)k * 1024 + n];
  out[(size_t)m * 1024 + n] = acc + bv[n];
}

// ---------------------------------------------------------------------------
// 4. Per-series correlation via radix-8/4 Stockham FFT + radix-select top-22
//    + softmax + mod-8 agg. One 256-thread block per series s = b*1024 + n.
//    (verified in rounds 2-5; unchanged)
// ---------------------------------------------------------------------------
__global__ __launch_bounds__(256, 4) void corr_topk(
    const unsigned short* __restrict__ Qt,
    const unsigned short* Kt,
    const float* __restrict__ vsmall,
    unsigned short* corrOut,
    float* __restrict__ agg) {
  __shared__ __align__(16) float bufA[4224];  // 2048 complex + pad (16.5 KB)
  __shared__ __align__(16) float bufB[4224];

  const int tid = threadIdx.x;
  const int lane = tid & 63;
  const int wv = tid >> 6;
  const int s = blockIdx.x;
  const size_t base = (size_t)s * 2048;

  // selection scratch aliased into bufB (dead after inv stage 3 barrier)
  unsigned int* hist = reinterpret_cast<unsigned int*>(bufB);  // [4][256]
  float* bins = bufB + 1024;                                   // [8]
  float* wred = bufB + 1032;                                   // [4]
  int* ired = reinterpret_cast<int*>(bufB + 1036);             // [4]
  unsigned int* sb = reinterpret_cast<unsigned int*>(bufB + 1040);  // [2]

  // ---- forward stage 1 (R8, Ns=1, r=0): strided global loads -> bufA ----
  {
    float2 v[8];
#pragma unroll
    for (int m = 0; m < 8; ++m) {
      const int u = tid + (m << 8);
      v[m] = make2(bf2f(Qt[base + u]), bf2f(Kt[base + u]));
    }
    dft8<false>(v);
    const int d = tid << 3;
#pragma unroll
    for (int m = 0; m < 8; ++m)
      *reinterpret_cast<float2*>(bufA + cfi(d + m)) = v[m];
  }
  __syncthreads();

  stage8<8, false>(bufA, bufB, tid);
  __syncthreads();
  stage8<64, false>(bufB, bufA, tid);
  __syncthreads();

  // ---- forward stage 4 (R4, Ns=512): bufA -> bufB (Z, natural order) ----
  {
#pragma unroll
    for (int h = 0; h < 2; ++h) {
      const int j = tid + (h << 8);
      float2 v[4];
#pragma unroll
      for (int m = 0; m < 4; ++m)
        v[m] = *reinterpret_cast<const float2*>(bufA + cfi(j + (m << 9)));
      const float rev = -(1.0f / 2048.0f) * (float)j;
      float2 w1; w1.x = __builtin_amdgcn_cosf(rev); w1.y = __builtin_amdgcn_sinf(rev);
      const float2 w2 = cmul(w1, w1);
      const float2 w3 = cmul(w2, w1);
      v[1] = cmul(v[1], w1); v[2] = cmul(v[2], w2); v[3] = cmul(v[3], w3);
      dft4<false>(v);
#pragma unroll
      for (int m = 0; m < 4; ++m)
        *reinterpret_cast<float2*>(bufB + cfi(j + (m << 9))) = v[m];
    }
  }
  __syncthreads();

  // ---- inverse stage 1 (R8, Ns=1) with fused spectrum: bufB -> bufA ----
  {
    float2 v[8];
    const float ks = 1.0f / 8192.0f;
#pragma unroll
    for (int m = 0; m < 8; ++m) {
      const int u = tid + (m << 8);
      const int ub = (2048 - u) & 2047;
      const float2 Av = *reinterpret_cast<const float2*>(bufB + cfi(u));
      const float2 Bv = *reinterpret_cast<const float2*>(bufB + cfi(ub));
      const float Px = Av.x + Bv.x, Py = Av.y - Bv.y;
      const float Qx = Av.x - Bv.x, Qy = -Av.y - Bv.y;
      const float X1 = (Px * Qx - Py * Qy) * ks;
      const float Y1 = (Px * Qy + Py * Qx) * ks;
      v[m] = make2(-Y1, X1);
    }
    dft8<true>(v);
    const int d = tid << 3;
#pragma unroll
    for (int m = 0; m < 8; ++m)
      *reinterpret_cast<float2*>(bufA + cfi(d + m)) = v[m];
  }
  __syncthreads();

  stage8<8, true>(bufA, bufB, tid);
  __syncthreads();
  stage8<64, true>(bufB, bufA, tid);
  __syncthreads();
  // bufB is DEAD from here on -> reused as selection scratch.

  // ---- inverse stage 4 (R4, Ns=512) in registers; real part only ----
  float cval[8];
#pragma unroll
  for (int h = 0; h < 2; ++h) {
    const int j = tid + (h << 8);
    float2 v0 = *reinterpret_cast<const float2*>(bufA + cfi(j));
    float2 v1 = *reinterpret_cast<const float2*>(bufA + cfi(j + 512));
    float2 v2 = *reinterpret_cast<const float2*>(bufA + cfi(j + 1024));
    float2 v3 = *reinterpret_cast<const float2*>(bufA + cfi(j + 1536));
    const float rev = (1.0f / 2048.0f) * (float)j;
    float2 w1; w1.x = __builtin_amdgcn_cosf(rev); w1.y = __builtin_amdgcn_sinf(rev);
    const float2 w2 = cmul(w1, w1);
    const float2 w3 = cmul(w2, w1);
    const float2 t1 = cmul(v1, w1);
    const float2 t3 = cmul(v3, w3);
    const float t2x = v2.x * w2.x - v2.y * w2.y;
    cval[h]     = v0.x + t1.x + t2x + t3.x;  // m=0
    cval[h + 2] = v0.x - t1.y - t2x + t3.y;  // m=1 (inv: +i twiddle)
    cval[h + 4] = v0.x - t1.x + t2x - t3.x;  // m=2
    cval[h + 6] = v0.x + t1.y - t2x - t3.y;  // m=3
  }

  // ---- write corr (bf16) to global; indices g = tid + 256*i, coalesced ----
#pragma unroll
  for (int i = 0; i < 8; ++i)
    corrOut[base + (size_t)(tid + (i << 8))] = f2bf(cval[i]);

  // ---- monotone float->uint keys ----
  unsigned int key[8];
#pragma unroll
  for (int i = 0; i < 8; ++i) {
    union { float f; unsigned int u; } cvt;
    cvt.f = cval[i];
    const unsigned int b = cvt.u;
    key[i] = (b & 0x80000000u) ? ~b : (b | 0x80000000u);
  }

  // ---- zero hist+bins, block max (both land in the same barrier) ----
#pragma unroll
  for (int q = 0; q < 4; ++q) hist[(q << 8) + tid] = 0u;
  if (tid < 8) bins[tid] = 0.f;
  {
    float vm = cval[0];
#pragma unroll
    for (int i = 1; i < 8; ++i) vm = fmaxf(vm, cval[i]);
#pragma unroll
    for (int off = 32; off > 0; off >>= 1) vm = fmaxf(vm, __shfl_down(vm, off));
    if (lane == 0) wred[wv] = vm;
  }
  __syncthreads();
  const float mx = fmaxf(fmaxf(wred[0], wred[1]), fmaxf(wred[2], wred[3]));

  // ---- 4 radix rounds: find 22nd-largest key ----
  unsigned int prefix = 0;
  unsigned int need = TOPK;
  // round 3 (bits 31:24), no prefix check
#pragma unroll
  for (int i = 0; i < 8; ++i) atomicAdd(&hist[key[i] >> 24], 1u);
  __syncthreads();
  radix_pick(hist, sb, need, tid);
  __syncthreads();
  prefix = sb[0]; need = sb[1];
  // round 2 (bits 23:16)
#pragma unroll
  for (int i = 0; i < 8; ++i)
    if ((key[i] >> 24) == prefix) atomicAdd(&hist[256 + ((key[i] >> 16) & 255u)], 1u);
  __syncthreads();
  radix_pick(hist + 256, sb, need, tid);
  __syncthreads();
  prefix = (prefix << 8) | sb[0]; need = sb[1];
  // round 1 (bits 15:8)
#pragma unroll
  for (int i = 0; i < 8; ++i)
    if ((key[i] >> 16) == prefix) atomicAdd(&hist[512 + ((key[i] >> 8) & 255u)], 1u);
  __syncthreads();
  radix_pick(hist + 512, sb, need, tid);
  __syncthreads();
  prefix = (prefix << 8) | sb[0]; need = sb[1];
  // round 0 (bits 7:0)
#pragma unroll
  for (int i = 0; i < 8; ++i)
    if ((key[i] >> 8) == prefix) atomicAdd(&hist[768 + (key[i] & 255u)], 1u);
  __syncthreads();
  radix_pick(hist + 768, sb, need, tid);
  __syncthreads();
  const unsigned int T = (prefix << 8) | sb[0];  // exact 22nd-largest key
  const unsigned int takeEq = sb[1];             // # of ==T to take (>=1)

  // ---- tie resolution: takeEq smallest indices among key==T ----
  unsigned int eqm = 0, selEq = 0;
#pragma unroll
  for (int i = 0; i < 8; ++i)
    if (key[i] == T) eqm |= (1u << i);
  for (unsigned int it2 = 0; it2 < takeEq; ++it2) {
    int mi = 0x7fffffff;
#pragma unroll
    for (int i = 0; i < 8; ++i)
      if (eqm & (1u << i)) mi = min(mi, tid + (i << 8));
#pragma unroll
    for (int off = 32; off > 0; off >>= 1) {
      const int o = __shfl_down(mi, off);
      if (lane + off < 64) mi = min(mi, o);
    }
    if (lane == 0) ired[wv] = mi;
    __syncthreads();
    const int gm = min(min(ired[0], ired[1]), min(ired[2], ired[3]));
#pragma unroll
    for (int i = 0; i < 8; ++i)
      if ((tid + (i << 8)) == gm) { selEq |= (1u << i); eqm &= ~(1u << i); }
    if (it2 + 1 < takeEq) __syncthreads();
  }

  // ---- softmax bin accumulation: all of this thread's g share bin tid&7 ----
  float esum = 0.f;
#pragma unroll
  for (int i = 0; i < 8; ++i) {
    const bool sel = (key[i] > T) || ((selEq >> i) & 1u);
    if (sel) esum += __expf(cval[i] - mx);
  }
  if (esum > 0.f) atomicAdd(&bins[tid & 7], esum);
  __syncthreads();

  if (tid < 8) {  // agg8[r] = sum_c (bins[c]/ssum) * v[(r+c)&7]
    const float ssum = bins[0] + bins[1] + bins[2] + bins[3] +
                       bins[4] + bins[5] + bins[6] + bins[7];
    const int b = s >> 10, n = s & 1023;
    float a = 0.f;
#pragma unroll
    for (int c = 0; c < 8; ++c)
      a += bins[c] * vsmall[(size_t)(b * 8 + ((tid + c) & 7)) * 1024 + n];
    agg[(size_t)(b * 8 + tid) * 1024 + n] = a / ssum;
  }
}

// ---------------------------------------------------------------------------
// 5. corrWs[b*1024+n][l] (bf16) -> out1[b][l][n] (fp32 tiled transpose)
//    MUST run BEFORE osmall_bcast (corrWs lives in the out0 region).
// ---------------------------------------------------------------------------
__global__ __launch_bounds__(256) void corr_transpose(
    const unsigned short* __restrict__ corrWs,
    float* __restrict__ out1) {
  __shared__ unsigned short T[64][72];
  const int bb = blockIdx.z;
  const int l0 = blockIdx.x * 64;
  const int n0 = blockIdx.y * 64;
  const int c = threadIdx.x & 63;
  const int r0 = threadIdx.x >> 6;
#pragma unroll
  for (int p = 0; p < 16; ++p) {
    const int r = r0 + 4 * p;  // n-local
    T[c][r] = corrWs[(size_t)(bb * 1024 + n0 + r) * 2048 + l0 + c];
  }
  __syncthreads();
#pragma unroll
  for (int p = 0; p < 16; ++p) {
    const int ll = r0 + 4 * p;  // l-local
    out1[(size_t)(bb * 2048 + l0 + ll) * 1024 + n0 + c] = bf2f(T[ll][c]);
  }
}

// ---------------------------------------------------------------------------
// 6. Output projection fused with mod-8 broadcast: for m = b*8+t,
//    acc = agg[m] @ Wo[:,n] + bo[n]; out0[b][l][n] = acc for all l&7==t.
//    Fully overwrites out0. Runs LAST (after corr_transpose freed out0).
// ---------------------------------------------------------------------------
__global__ __launch_bounds__(256) void osmall_bcast(
    const float* __restrict__ aggin,
    const float* __restrict__ Wo,
    const float* __restrict__ bo,
    float* __restrict__ out0) {
  __shared__ float xr[1024];
  const int m = blockIdx.x;  // 0..63
  const int b = m >> 3, t = m & 7;
  const float* row = aggin + (size_t)m * 1024;
  for (int i = threadIdx.x; i < 1024; i += 256) xr[i] = row[i];
  __syncthreads();
  const int n = blockIdx.y * 256 + threadIdx.x;
  float acc = 0.f;
#pragma unroll 8
  for (int k = 0; k < 1024; ++k) acc += xr[k] * Wo[(size_t)k * 1024 + n];
  acc += bo[n];
  float* o = out0 + ((size_t)b * 2048 + t) * 1024 + n;
#pragma unroll 4
  for (int l8 = 0; l8 < 256; ++l8)       // rows l = t + 8*l8
    o[(size_t)l8 * 8192] = acc;
}

// ---------------------------------------------------------------------------
extern "C" void kernel_launch(void* const* d_in, const int* in_sizes, int n_in,
                              void* d_out, int out_size, void* d_ws, size_t ws_size,
                              hipStream_t stream) {
  const float* queries = (const float*)d_in[0];
  const float* keys    = (const float*)d_in[1];
  const float* values  = (const float*)d_in[2];
  const float* Wq = (const float*)d_in[3];
  const float* bq = (const float*)d_in[4];
  const float* Wk = (const float*)d_in[5];
  const float* bk = (const float*)d_in[6];
  const float* Wv = (const float*)d_in[7];
  const float* bv = (const float*)d_in[8];
  const float* Wo = (const float*)d_in[9];
  const float* bo = (const float*)d_in[10];

  char* ws = (char*)d_ws;
  unsigned short* WqT = (unsigned short*)(ws);                    // 2 MiB bf16
  unsigned short* WkT = (unsigned short*)(ws + (2u << 20));       // 2 MiB bf16
  unsigned short* Qt  = (unsigned short*)(ws + (4u << 20));       // 32 MiB bf16 [B*D, L]
  float* vsmall   = (float*)(ws + (36u << 20));                   // 256 KiB
  float* aggbuf   = (float*)(ws + (36u << 20) + (256u << 10));    // 256 KiB
  // total ws: 36.5 MiB

  float* out0 = (float*)d_out;                   // [8,2048,1024] fp32
  float* out1 = out0 + (size_t)16777216;         // [8,2048,1024] fp32
  // Kt bf16 staging (32 MiB) lives in the out0 region (64 MiB fp32);
  // corr output aliases it row-by-row; osmall_bcast overwrites out0 last.
  unsigned short* Kt = (unsigned short*)d_out;
  unsigned short* corrWs = Kt;

  transpose_w<<<dim3(16, 16, 2), 256, 0, stream>>>(Wq, Wk, WqT, WkT);
  gemm_qk<<<1024, 256, 0, stream>>>(queries, WqT, bq, Qt);
  gemm_qk<<<1024, 256, 0, stream>>>(keys, WkT, bk, Kt);
  vsmall_kernel<<<dim3(64, 4), 256, 0, stream>>>(values, Wv, bv, vsmall);
  corr_topk<<<8192, 256, 0, stream>>>(Qt, Kt, vsmall, corrWs, aggbuf);
  corr_transpose<<<dim3(32, 16, 8), 256, 0, stream>>>(corrWs, out1);
  osmall_bcast<<<dim3(64, 4), 256, 0, stream>>>(aggbuf, Wo, bo, out0);
}

// Round 8
// 610.228 us; speedup vs baseline: 1.0742x; 1.0742x over previous
//
#include <hip/hip_runtime.h>
#include <cstdint>
#include <cstddef>

// ---------------------------------------------------------------------------
// AutoFormer forward, MI355X. ALL inputs/outputs are FP32 (per reference).
// Q/K projections: single merged MFMA GEMM dispatch (z selects Q/K), inline
// fp32->bf16 A staging (round-3 best-measured config).
// corr via FFT, radix-8/4 Stockham; top-22 via radix-select; softmax mod-8.
// Output projection fused with the mod-8 broadcast (osmall_bcast).
// B=8, L=2048, D=1024, H=16, E=64, TOPK=22.
//
// Buffers:
//   ws:    WqT/WkT (bf16, 2 MiB ea), Qt (bf16 [B*D,L], 32 MiB), smalls (<1 MiB)
//   d_out: out0 region [16M fp32] doubles as Kt/corrWs bf16 staging (32 MiB);
//          corr_topk aliases corr rows over Kt; corr_transpose consumes them
//          into out1; osmall_bcast overwrites out0 LAST.
// ---------------------------------------------------------------------------

#define TOPK 22

typedef __attribute__((ext_vector_type(8))) short short8;
typedef __attribute__((ext_vector_type(4))) float f32x4;

__device__ __forceinline__ float bf2f(unsigned short u) {
  union { unsigned int i; float f; } w;
  w.i = ((unsigned int)u) << 16;
  return w.f;
}
__device__ __forceinline__ unsigned short f2bf(float f) {
  union { float f; unsigned int i; } w;
  w.f = f;
  unsigned int x = w.i;
  x += 0x7fffu + ((x >> 16) & 1u);  // RNE
  return (unsigned short)(x >> 16);
}

__device__ __forceinline__ float2 make2(float x, float y) { float2 r; r.x = x; r.y = y; return r; }
__device__ __forceinline__ float2 cadd(float2 a, float2 b) { return make2(a.x + b.x, a.y + b.y); }
__device__ __forceinline__ float2 csub(float2 a, float2 b) { return make2(a.x - b.x, a.y - b.y); }
__device__ __forceinline__ float2 cmul(float2 a, float2 b) {
  return make2(a.x * b.x - a.y * b.y, a.x * b.y + a.y * b.x);
}

// padded complex->float index: 2 pad floats per 32 complex; keeps 8B align.
__device__ __forceinline__ int cfi(int u) { return 2 * u + (((u) >> 5) << 1); }

// 8-point DFT in registers. INV=false: e^{-2pi i/8}; INV=true: conj.
template <bool INV>
__device__ __forceinline__ void dft8(float2 (&v)[8]) {
  const float C = 0.70710678118654752f;
  // evens DFT4
  float2 s0 = cadd(v[0], v[4]), s1 = csub(v[0], v[4]);
  float2 s2 = cadd(v[2], v[6]), s3 = csub(v[2], v[6]);
  float2 E0 = cadd(s0, s2), E2 = csub(s0, s2);
  float2 E1, E3;
  if (!INV) { E1 = make2(s1.x + s3.y, s1.y - s3.x); E3 = make2(s1.x - s3.y, s1.y + s3.x); }
  else      { E1 = make2(s1.x - s3.y, s1.y + s3.x); E3 = make2(s1.x + s3.y, s1.y - s3.x); }
  // odds DFT4
  float2 q0 = cadd(v[1], v[5]), q1 = csub(v[1], v[5]);
  float2 q2 = cadd(v[3], v[7]), q3 = csub(v[3], v[7]);
  float2 O0 = cadd(q0, q2), O2 = csub(q0, q2);
  float2 O1, O3;
  if (!INV) { O1 = make2(q1.x + q3.y, q1.y - q3.x); O3 = make2(q1.x - q3.y, q1.y + q3.x); }
  else      { O1 = make2(q1.x - q3.y, q1.y + q3.x); O3 = make2(q1.x + q3.y, q1.y - q3.x); }
  // twiddle odds by w8^m
  float2 T0 = O0, T1, T2, T3;
  if (!INV) {
    T1 = make2(C * (O1.x + O1.y), C * (O1.y - O1.x));   // *(1-i)/sqrt2
    T2 = make2(O2.y, -O2.x);                            // *(-i)
    T3 = make2(C * (O3.y - O3.x), -C * (O3.x + O3.y));  // *(-(1+i)/sqrt2)
  } else {
    T1 = make2(C * (O1.x - O1.y), C * (O1.x + O1.y));   // *(1+i)/sqrt2
    T2 = make2(-O2.y, O2.x);                            // *(+i)
    T3 = make2(-C * (O3.x + O3.y), C * (O3.x - O3.y));  // *((-1+i)/sqrt2)
  }
  v[0] = cadd(E0, T0); v[4] = csub(E0, T0);
  v[1] = cadd(E1, T1); v[5] = csub(E1, T1);
  v[2] = cadd(E2, T2); v[6] = csub(E2, T2);
  v[3] = cadd(E3, T3); v[7] = csub(E3, T3);
}

template <bool INV>
__device__ __forceinline__ void dft4(float2 (&v)[4]) {
  float2 s0 = cadd(v[0], v[2]), s1 = csub(v[0], v[2]);
  float2 s2 = cadd(v[1], v[3]), s3 = csub(v[1], v[3]);
  v[0] = cadd(s0, s2); v[2] = csub(s0, s2);
  if (!INV) { v[1] = make2(s1.x + s3.y, s1.y - s3.x); v[3] = make2(s1.x - s3.y, s1.y + s3.x); }
  else      { v[1] = make2(s1.x - s3.y, s1.y + s3.x); v[3] = make2(s1.x + s3.y, s1.y - s3.x); }
}

// Stockham radix-8 LDS stage. Reads src[j+256m], writes dst[d+m*NS],
// d = (j div NS)*8NS + r, twiddle w^(r*m), w = e^{sigma*2pi i*r/(8NS)}.
template <int NS, bool INV>
__device__ __forceinline__ void stage8(const float* __restrict__ src,
                                       float* __restrict__ dst, int tid) {
  float2 v[8];
#pragma unroll
  for (int m = 0; m < 8; ++m)
    v[m] = *reinterpret_cast<const float2*>(src + cfi(tid + (m << 8)));
  if constexpr (NS > 1) {
    const int r = tid & (NS - 1);
    const float rev = (INV ? (1.0f / (8 * NS)) : (-1.0f / (8 * NS))) * (float)r;
    float2 w1; w1.x = __builtin_amdgcn_cosf(rev); w1.y = __builtin_amdgcn_sinf(rev);
    const float2 w2 = cmul(w1, w1);
    const float2 w3 = cmul(w2, w1);
    const float2 w4 = cmul(w2, w2);
    const float2 w5 = cmul(w4, w1);
    const float2 w6 = cmul(w4, w2);
    const float2 w7 = cmul(w4, w3);
    v[1] = cmul(v[1], w1); v[2] = cmul(v[2], w2); v[3] = cmul(v[3], w3);
    v[4] = cmul(v[4], w4); v[5] = cmul(v[5], w5); v[6] = cmul(v[6], w6);
    v[7] = cmul(v[7], w7);
  }
  dft8<INV>(v);
  const int r2 = tid & (NS - 1);
  const int d = ((tid & ~(NS - 1)) << 3) | r2;
#pragma unroll
  for (int m = 0; m < 8; ++m)
    *reinterpret_cast<float2*>(dst + cfi(d + m * NS)) = v[m];
}

// radix-select pick phase: wave 0 scans a 256-bin histogram from the top,
// finds bin containing the 'need'-th largest; writes {bin, need_within_bin}.
__device__ __forceinline__ void radix_pick(const unsigned int* h,
                                           unsigned int* sb,
                                           unsigned int need, int tid) {
  if (tid < 64) {
    const unsigned int c0 = h[4 * tid + 0];
    const unsigned int c1 = h[4 * tid + 1];
    const unsigned int c2 = h[4 * tid + 2];
    const unsigned int c3 = h[4 * tid + 3];
    const unsigned int g = c0 + c1 + c2 + c3;
    unsigned int S = g;  // suffix-inclusive scan over 64 groups
#pragma unroll
    for (int off = 1; off < 64; off <<= 1) {
      const unsigned int o = __shfl_down(S, off);
      if (tid + off < 64) S += o;
    }
    unsigned int A = S - g;  // count in bins strictly above this group
    int pick = -1;
    unsigned int nn = 0;
    const unsigned int cc[4] = {c0, c1, c2, c3};
#pragma unroll
    for (int j = 3; j >= 0; --j) {
      if (pick < 0) {
        if (A < need && need <= A + cc[j]) { pick = j; nn = need - A; }
        else A += cc[j];
      }
    }
    if (pick >= 0) { sb[0] = (unsigned int)(4 * tid + pick); sb[1] = nn; }
  }
}

// ---------------------------------------------------------------------------
// 1. Weight transpose + fp32->bf16: WT[n][k] = bf16(W[k][n]), z=0:Wq z=1:Wk
// ---------------------------------------------------------------------------
__global__ __launch_bounds__(256) void transpose_w(
    const float* __restrict__ Wq, const float* __restrict__ Wk,
    unsigned short* __restrict__ WqT, unsigned short* __restrict__ WkT) {
  __shared__ unsigned short T[64][72];
  const float* src = blockIdx.z ? Wk : Wq;
  unsigned short* dst = blockIdx.z ? WkT : WqT;
  const int k0 = blockIdx.x * 64;
  const int n0 = blockIdx.y * 64;
  const int c = threadIdx.x & 63;
  const int r0 = threadIdx.x >> 6;
#pragma unroll
  for (int p = 0; p < 16; ++p) {
    const int r = r0 + 4 * p;  // k-local
    T[c][r] = f2bf(src[(size_t)(k0 + r) * 1024 + n0 + c]);  // coalesced read
  }
  __syncthreads();
#pragma unroll
  for (int p = 0; p < 16; ++p) {
    const int nn = r0 + 4 * p;  // n-local
    dst[(size_t)(n0 + nn) * 1024 + k0 + c] = T[nn][c];  // coalesced write
  }
}

// ---------------------------------------------------------------------------
// 2. MFMA bf16 GEMM (round-3 best-measured config), merged Q/K via blockIdx.z:
//    out = A(fp32)[16384,1024] @ W + bias(fp32), written transposed bf16 as
//    outT[b*1024+n][l]. Tile 128x128, BK=32, 4 waves, 16x16x32 MFMA.
//    A converted fp32->bf16 during staging; WT already bf16. Grid (128,8,2),
//    M-fastest order: 128 consecutive blocks share one 256 KB B panel (L2).
// ---------------------------------------------------------------------------
__global__ __launch_bounds__(256, 2) void gemm_qk(
    const float* __restrict__ Aq, const float* __restrict__ Ak,
    const unsigned short* __restrict__ WqT, const unsigned short* __restrict__ WkT,
    const float* __restrict__ bq, const float* __restrict__ bk,
    unsigned short* __restrict__ outQ, unsigned short* __restrict__ outK) {
  __shared__ __align__(16) unsigned short smem[16384];  // 32 KB
  unsigned short* As = smem;         // [128][32]
  unsigned short* Bs = smem + 4096;  // [128][32]

  const int z = blockIdx.z;
  const float* A = z ? Ak : Aq;
  const unsigned short* WT = z ? WkT : WqT;
  const float* bias = z ? bk : bq;
  unsigned short* outT = z ? outK : outQ;

  const int tid = threadIdx.x;
  const int lane = tid & 63;
  const int w = tid >> 6;
  const int wr = w >> 1, wc = w & 1;
  const int m0 = blockIdx.x * 128;
  const int n0 = blockIdx.y * 128;
  const int l15 = lane & 15;
  const int quad = lane >> 4;

  f32x4 acc[4][4];
#pragma unroll
  for (int i = 0; i < 4; ++i)
#pragma unroll
    for (int j = 0; j < 4; ++j)
#pragma unroll
      for (int r = 0; r < 4; ++r) acc[i][j][r] = 0.f;

  for (int k0 = 0; k0 < 1024; k0 += 32) {
    __syncthreads();
#pragma unroll
    for (int h = 0; h < 2; ++h) {
      const int c = tid + h * 256;  // chunk 0..511
      const int row = c >> 2;       // 0..127
      const int kc = (c & 3) * 8;   // element offset in row
      // A: 8 fp32 -> 8 bf16
      const float* ap = A + (size_t)(m0 + row) * 1024 + k0 + kc;
      const float4 a0 = *reinterpret_cast<const float4*>(ap);
      const float4 a1 = *reinterpret_cast<const float4*>(ap + 4);
      uint4 pa;
      pa.x = f2bf(a0.x) | ((unsigned int)f2bf(a0.y) << 16);
      pa.y = f2bf(a0.z) | ((unsigned int)f2bf(a0.w) << 16);
      pa.z = f2bf(a1.x) | ((unsigned int)f2bf(a1.y) << 16);
      pa.w = f2bf(a1.z) | ((unsigned int)f2bf(a1.w) << 16);
      *reinterpret_cast<uint4*>(As + row * 32 + kc) = pa;
      // B: already bf16
      uint4 vb = *reinterpret_cast<const uint4*>(WT + (size_t)(n0 + row) * 1024 + k0 + kc);
      *reinterpret_cast<uint4*>(Bs + row * 32 + kc) = vb;
    }
    __syncthreads();

    short8 af[4], bfr[4];
#pragma unroll
    for (int mt = 0; mt < 4; ++mt)
      af[mt] = *reinterpret_cast<const short8*>(As + (wr * 64 + mt * 16 + l15) * 32 + quad * 8);
#pragma unroll
    for (int nt = 0; nt < 4; ++nt)
      bfr[nt] = *reinterpret_cast<const short8*>(Bs + (wc * 64 + nt * 16 + l15) * 32 + quad * 8);
#pragma unroll
    for (int mt = 0; mt < 4; ++mt)
#pragma unroll
      for (int nt = 0; nt < 4; ++nt)
        acc[mt][nt] = __builtin_amdgcn_mfma_f32_16x16x32_bf16(af[mt], bfr[nt], acc[mt][nt], 0, 0, 0);
  }

  __syncthreads();
  // epilogue: bias + pack transposed into LDS Cs[n_local][m_local] (bf16)
  unsigned short* Cs = smem;  // [128][128] bf16 = 32 KB
#pragma unroll
  for (int nt = 0; nt < 4; ++nt) {
    const int n_local = wc * 64 + nt * 16 + l15;
    const float bv = bias[n0 + n_local];
#pragma unroll
    for (int mt = 0; mt < 4; ++mt) {
      const int mbase = wr * 64 + mt * 16 + quad * 4;
#pragma unroll
      for (int r = 0; r < 4; ++r)
        Cs[n_local * 128 + mbase + r] = f2bf(acc[mt][nt][r] + bv);
    }
  }
  __syncthreads();

  const int b = m0 >> 11;    // m0 / 2048
  const int l0 = m0 & 2047;
  for (int it = tid; it < 2048; it += 256) {
    const int rowi = it >> 4;  // n_local
    const int ci = it & 15;    // 16B chunk
    uint4 v = *reinterpret_cast<const uint4*>(Cs + rowi * 128 + ci * 8);
    *reinterpret_cast<uint4*>(outT + (size_t)(b * 1024 + n0 + rowi) * 2048 + l0 + ci * 8) = v;
  }
}

// ---------------------------------------------------------------------------
// 3. V projection, rows l=0..7 only (the %8 quirk): vsmall[b*8+t][n] fp32
// ---------------------------------------------------------------------------
__global__ __launch_bounds__(256) void vsmall_kernel(
    const float* __restrict__ values,
    const float* __restrict__ Wv,
    const float* __restrict__ bv,
    float* __restrict__ out) {
  __shared__ float xr[1024];
  const int m = blockIdx.x;  // 0..63
  const int b = m >> 3, t = m & 7;
  const float* row = values + ((size_t)b * 2048 + t) * 1024;
  for (int i = threadIdx.x; i < 1024; i += 256) xr[i] = row[i];
  __syncthreads();
  const int n = blockIdx.y * 256 + threadIdx.x;
  float acc = 0.f;
#pragma unroll 8
  for (int k = 0; k < 1024; ++k) acc += xr[k] * Wv[(size_t)k * 1024 + n];
  out[(size_t)m * 1024 + n] = acc + bv[n];
}

// ---------------------------------------------------------------------------
// 4. Per-series correlation via radix-8/4 Stockham FFT + radix-select top-22
//    + softmax + mod-8 agg. One 256-thread block per series s = b*1024 + n.
//    (verified in rounds 2-6; unchanged)
// ---------------------------------------------------------------------------
__global__ __launch_bounds__(256, 4) void corr_topk(
    const unsigned short* __restrict__ Qt,
    const unsigned short* Kt,
    const float* __restrict__ vsmall,
    unsigned short* corrOut,
    float* __restrict__ agg) {
  __shared__ __align__(16) float bufA[4224];  // 2048 complex + pad (16.5 KB)
  __shared__ __align__(16) float bufB[4224];

  const int tid = threadIdx.x;
  const int lane = tid & 63;
  const int wv = tid >> 6;
  const int s = blockIdx.x;
  const size_t base = (size_t)s * 2048;

  // selection scratch aliased into bufB (dead after inv stage 3 barrier)
  unsigned int* hist = reinterpret_cast<unsigned int*>(bufB);  // [4][256]
  float* bins = bufB + 1024;                                   // [8]
  float* wred = bufB + 1032;                                   // [4]
  int* ired = reinterpret_cast<int*>(bufB + 1036);             // [4]
  unsigned int* sb = reinterpret_cast<unsigned int*>(bufB + 1040);  // [2]

  // ---- forward stage 1 (R8, Ns=1, r=0): strided global loads -> bufA ----
  {
    float2 v[8];
#pragma unroll
    for (int m = 0; m < 8; ++m) {
      const int u = tid + (m << 8);
      v[m] = make2(bf2f(Qt[base + u]), bf2f(Kt[base + u]));
    }
    dft8<false>(v);
    const int d = tid << 3;
#pragma unroll
    for (int m = 0; m < 8; ++m)
      *reinterpret_cast<float2*>(bufA + cfi(d + m)) = v[m];
  }
  __syncthreads();

  stage8<8, false>(bufA, bufB, tid);
  __syncthreads();
  stage8<64, false>(bufB, bufA, tid);
  __syncthreads();

  // ---- forward stage 4 (R4, Ns=512): bufA -> bufB (Z, natural order) ----
  {
#pragma unroll
    for (int h = 0; h < 2; ++h) {
      const int j = tid + (h << 8);
      float2 v[4];
#pragma unroll
      for (int m = 0; m < 4; ++m)
        v[m] = *reinterpret_cast<const float2*>(bufA + cfi(j + (m << 9)));
      const float rev = -(1.0f / 2048.0f) * (float)j;
      float2 w1; w1.x = __builtin_amdgcn_cosf(rev); w1.y = __builtin_amdgcn_sinf(rev);
      const float2 w2 = cmul(w1, w1);
      const float2 w3 = cmul(w2, w1);
      v[1] = cmul(v[1], w1); v[2] = cmul(v[2], w2); v[3] = cmul(v[3], w3);
      dft4<false>(v);
#pragma unroll
      for (int m = 0; m < 4; ++m)
        *reinterpret_cast<float2*>(bufB + cfi(j + (m << 9))) = v[m];
    }
  }
  __syncthreads();

  // ---- inverse stage 1 (R8, Ns=1) with fused spectrum: bufB -> bufA ----
  {
    float2 v[8];
    const float ks = 1.0f / 8192.0f;
#pragma unroll
    for (int m = 0; m < 8; ++m) {
      const int u = tid + (m << 8);
      const int ub = (2048 - u) & 2047;
      const float2 Av = *reinterpret_cast<const float2*>(bufB + cfi(u));
      const float2 Bv = *reinterpret_cast<const float2*>(bufB + cfi(ub));
      const float Px = Av.x + Bv.x, Py = Av.y - Bv.y;
      const float Qx = Av.x - Bv.x, Qy = -Av.y - Bv.y;
      const float X1 = (Px * Qx - Py * Qy) * ks;
      const float Y1 = (Px * Qy + Py * Qx) * ks;
      v[m] = make2(-Y1, X1);
    }
    dft8<true>(v);
    const int d = tid << 3;
#pragma unroll
    for (int m = 0; m < 8; ++m)
      *reinterpret_cast<float2*>(bufA + cfi(d + m)) = v[m];
  }
  __syncthreads();

  stage8<8, true>(bufA, bufB, tid);
  __syncthreads();
  stage8<64, true>(bufB, bufA, tid);
  __syncthreads();
  // bufB is DEAD from here on -> reused as selection scratch.

  // ---- inverse stage 4 (R4, Ns=512) in registers; real part only ----
  float cval[8];
#pragma unroll
  for (int h = 0; h < 2; ++h) {
    const int j = tid + (h << 8);
    float2 v0 = *reinterpret_cast<const float2*>(bufA + cfi(j));
    float2 v1 = *reinterpret_cast<const float2*>(bufA + cfi(j + 512));
    float2 v2 = *reinterpret_cast<const float2*>(bufA + cfi(j + 1024));
    float2 v3 = *reinterpret_cast<const float2*>(bufA + cfi(j + 1536));
    const float rev = (1.0f / 2048.0f) * (float)j;
    float2 w1; w1.x = __builtin_amdgcn_cosf(rev); w1.y = __builtin_amdgcn_sinf(rev);
    const float2 w2 = cmul(w1, w1);
    const float2 w3 = cmul(w2, w1);
    const float2 t1 = cmul(v1, w1);
    const float2 t3 = cmul(v3, w3);
    const float t2x = v2.x * w2.x - v2.y * w2.y;
    cval[h]     = v0.x + t1.x + t2x + t3.x;  // m=0
    cval[h + 2] = v0.x - t1.y - t2x + t3.y;  // m=1 (inv: +i twiddle)
    cval[h + 4] = v0.x - t1.x + t2x - t3.x;  // m=2
    cval[h + 6] = v0.x + t1.y - t2x - t3.y;  // m=3
  }

  // ---- write corr (bf16) to global; indices g = tid + 256*i, coalesced ----
#pragma unroll
  for (int i = 0; i < 8; ++i)
    corrOut[base + (size_t)(tid + (i << 8))] = f2bf(cval[i]);

  // ---- monotone float->uint keys ----
  unsigned int key[8];
#pragma unroll
  for (int i = 0; i < 8; ++i) {
    union { float f; unsigned int u; } cvt;
    cvt.f = cval[i];
    const unsigned int b = cvt.u;
    key[i] = (b & 0x80000000u) ? ~b : (b | 0x80000000u);
  }

  // ---- zero hist+bins, block max (both land in the same barrier) ----
#pragma unroll
  for (int q = 0; q < 4; ++q) hist[(q << 8) + tid] = 0u;
  if (tid < 8) bins[tid] = 0.f;
  {
    float vm = cval[0];
#pragma unroll
    for (int i = 1; i < 8; ++i) vm = fmaxf(vm, cval[i]);
#pragma unroll
    for (int off = 32; off > 0; off >>= 1) vm = fmaxf(vm, __shfl_down(vm, off));
    if (lane == 0) wred[wv] = vm;
  }
  __syncthreads();
  const float mx = fmaxf(fmaxf(wred[0], wred[1]), fmaxf(wred[2], wred[3]));

  // ---- 4 radix rounds: find 22nd-largest key ----
  unsigned int prefix = 0;
  unsigned int need = TOPK;
  // round 3 (bits 31:24), no prefix check
#pragma unroll
  for (int i = 0; i < 8; ++i) atomicAdd(&hist[key[i] >> 24], 1u);
  __syncthreads();
  radix_pick(hist, sb, need, tid);
  __syncthreads();
  prefix = sb[0]; need = sb[1];
  // round 2 (bits 23:16)
#pragma unroll
  for (int i = 0; i < 8; ++i)
    if ((key[i] >> 24) == prefix) atomicAdd(&hist[256 + ((key[i] >> 16) & 255u)], 1u);
  __syncthreads();
  radix_pick(hist + 256, sb, need, tid);
  __syncthreads();
  prefix = (prefix << 8) | sb[0]; need = sb[1];
  // round 1 (bits 15:8)
#pragma unroll
  for (int i = 0; i < 8; ++i)
    if ((key[i] >> 16) == prefix) atomicAdd(&hist[512 + ((key[i] >> 8) & 255u)], 1u);
  __syncthreads();
  radix_pick(hist + 512, sb, need, tid);
  __syncthreads();
  prefix = (prefix << 8) | sb[0]; need = sb[1];
  // round 0 (bits 7:0)
#pragma unroll
  for (int i = 0; i < 8; ++i)
    if ((key[i] >> 8) == prefix) atomicAdd(&hist[768 + (key[i] & 255u)], 1u);
  __syncthreads();
  radix_pick(hist + 768, sb, need, tid);
  __syncthreads();
  const unsigned int T = (prefix << 8) | sb[0];  // exact 22nd-largest key
  const unsigned int takeEq = sb[1];             // # of ==T to take (>=1)

  // ---- tie resolution: takeEq smallest indices among key==T ----
  unsigned int eqm = 0, selEq = 0;
#pragma unroll
  for (int i = 0; i < 8; ++i)
    if (key[i] == T) eqm |= (1u << i);
  for (unsigned int it2 = 0; it2 < takeEq; ++it2) {
    int mi = 0x7fffffff;
#pragma unroll
    for (int i = 0; i < 8; ++i)
      if (eqm & (1u << i)) mi = min(mi, tid + (i << 8));
#pragma unroll
    for (int off = 32; off > 0; off >>= 1) {
      const int o = __shfl_down(mi, off);
      if (lane + off < 64) mi = min(mi, o);
    }
    if (lane == 0) ired[wv] = mi;
    __syncthreads();
    const int gm = min(min(ired[0], ired[1]), min(ired[2], ired[3]));
#pragma unroll
    for (int i = 0; i < 8; ++i)
      if ((tid + (i << 8)) == gm) { selEq |= (1u << i); eqm &= ~(1u << i); }
    if (it2 + 1 < takeEq) __syncthreads();
  }

  // ---- softmax bin accumulation: all of this thread's g share bin tid&7 ----
  float esum = 0.f;
#pragma unroll
  for (int i = 0; i < 8; ++i) {
    const bool sel = (key[i] > T) || ((selEq >> i) & 1u);
    if (sel) esum += __expf(cval[i] - mx);
  }
  if (esum > 0.f) atomicAdd(&bins[tid & 7], esum);
  __syncthreads();

  if (tid < 8) {  // agg8[r] = sum_c (bins[c]/ssum) * v[(r+c)&7]
    const float ssum = bins[0] + bins[1] + bins[2] + bins[3] +
                       bins[4] + bins[5] + bins[6] + bins[7];
    const int b = s >> 10, n = s & 1023;
    float a = 0.f;
#pragma unroll
    for (int c = 0; c < 8; ++c)
      a += bins[c] * vsmall[(size_t)(b * 8 + ((tid + c) & 7)) * 1024 + n];
    agg[(size_t)(b * 8 + tid) * 1024 + n] = a / ssum;
  }
}

// ---------------------------------------------------------------------------
// 5. corrWs[b*1024+n][l] (bf16) -> out1[b][l][n] (fp32 tiled transpose)
//    MUST run BEFORE osmall_bcast (corrWs lives in the out0 region).
// ---------------------------------------------------------------------------
__global__ __launch_bounds__(256) void corr_transpose(
    const unsigned short* __restrict__ corrWs,
    float* __restrict__ out1) {
  __shared__ unsigned short T[64][72];
  const int bb = blockIdx.z;
  const int l0 = blockIdx.x * 64;
  const int n0 = blockIdx.y * 64;
  const int c = threadIdx.x & 63;
  const int r0 = threadIdx.x >> 6;
#pragma unroll
  for (int p = 0; p < 16; ++p) {
    const int r = r0 + 4 * p;  // n-local
    T[c][r] = corrWs[(size_t)(bb * 1024 + n0 + r) * 2048 + l0 + c];
  }
  __syncthreads();
#pragma unroll
  for (int p = 0; p < 16; ++p) {
    const int ll = r0 + 4 * p;  // l-local
    out1[(size_t)(bb * 2048 + l0 + ll) * 1024 + n0 + c] = bf2f(T[ll][c]);
  }
}

// ---------------------------------------------------------------------------
// 6. Output projection fused with mod-8 broadcast: for m = b*8+t,
//    acc = agg[m] @ Wo[:,n] + bo[n]; out0[b][l][n] = acc for all l&7==t.
//    Fully overwrites out0. Runs LAST (after corr_transpose freed out0).
// ---------------------------------------------------------------------------
__global__ __launch_bounds__(256) void osmall_bcast(
    const float* __restrict__ aggin,
    const float* __restrict__ Wo,
    const float* __restrict__ bo,
    float* __restrict__ out0) {
  __shared__ float xr[1024];
  const int m = blockIdx.x;  // 0..63
  const int b = m >> 3, t = m & 7;
  const float* row = aggin + (size_t)m * 1024;
  for (int i = threadIdx.x; i < 1024; i += 256) xr[i] = row[i];
  __syncthreads();
  const int n = blockIdx.y * 256 + threadIdx.x;
  float acc = 0.f;
#pragma unroll 8
  for (int k = 0; k < 1024; ++k) acc += xr[k] * Wo[(size_t)k * 1024 + n];
  acc += bo[n];
  float* o = out0 + ((size_t)b * 2048 + t) * 1024 + n;
#pragma unroll 4
  for (int l8 = 0; l8 < 256; ++l8)       // rows l = t + 8*l8
    o[(size_t)l8 * 8192] = acc;
}

// ---------------------------------------------------------------------------
extern "C" void kernel_launch(void* const* d_in, const int* in_sizes, int n_in,
                              void* d_out, int out_size, void* d_ws, size_t ws_size,
                              hipStream_t stream) {
  const float* queries = (const float*)d_in[0];
  const float* keys    = (const float*)d_in[1];
  const float* values  = (const float*)d_in[2];
  const float* Wq = (const float*)d_in[3];
  const float* bq = (const float*)d_in[4];
  const float* Wk = (const float*)d_in[5];
  const float* bk = (const float*)d_in[6];
  const float* Wv = (const float*)d_in[7];
  const float* bv = (const float*)d_in[8];
  const float* Wo = (const float*)d_in[9];
  const float* bo = (const float*)d_in[10];

  char* ws = (char*)d_ws;
  unsigned short* WqT = (unsigned short*)(ws);                    // 2 MiB bf16
  unsigned short* WkT = (unsigned short*)(ws + (2u << 20));       // 2 MiB bf16
  unsigned short* Qt  = (unsigned short*)(ws + (4u << 20));       // 32 MiB bf16 [B*D, L]
  float* vsmall   = (float*)(ws + (36u << 20));                   // 256 KiB
  float* aggbuf   = (float*)(ws + (36u << 20) + (256u << 10));    // 256 KiB
  // total ws: 36.5 MiB

  float* out0 = (float*)d_out;                   // [8,2048,1024] fp32
  float* out1 = out0 + (size_t)16777216;         // [8,2048,1024] fp32
  // Kt bf16 staging (32 MiB) lives in the out0 region (64 MiB fp32);
  // corr output aliases it row-by-row; osmall_bcast overwrites out0 last.
  unsigned short* Kt = (unsigned short*)d_out;
  unsigned short* corrWs = Kt;

  transpose_w<<<dim3(16, 16, 2), 256, 0, stream>>>(Wq, Wk, WqT, WkT);
  gemm_qk<<<dim3(128, 8, 2), 256, 0, stream>>>(queries, keys, WqT, WkT, bq, bk, Qt, Kt);
  vsmall_kernel<<<dim3(64, 4), 256, 0, stream>>>(values, Wv, bv, vsmall);
  corr_topk<<<8192, 256, 0, stream>>>(Qt, Kt, vsmall, corrWs, aggbuf);
  corr_transpose<<<dim3(32, 16, 8), 256, 0, stream>>>(corrWs, out1);
  osmall_bcast<<<dim3(64, 4), 256, 0, stream>>>(aggbuf, Wo, bo, out0);
}